// Round 1
// baseline (190.914 us; speedup 1.0000x reference)
//
#include <hip/hip_runtime.h>
#include <hip/hip_bf16.h>
#include <stdint.h>

typedef __attribute__((ext_vector_type(8))) short short8;
typedef __attribute__((ext_vector_type(4))) float float4v;

#define SEQ   1024
#define NQKV  3072

__device__ __forceinline__ float bf2f(ushort h) {
    union { uint u; float f; } c; c.u = ((uint)h) << 16; return c.f;
}
__device__ __forceinline__ ushort f2bf(float f) {
    union { uint u; float f; } c; c.f = f;
    uint u = c.u;
    return (ushort)((u + 0x7fffu + ((u >> 16) & 1u)) >> 16);
}
__device__ __forceinline__ void gl2lds16(const ushort* g, ushort* l) {
    __builtin_amdgcn_global_load_lds(
        (const __attribute__((address_space(1))) unsigned int*)(g),
        (__attribute__((address_space(3))) unsigned int*)(l),
        16, 0, 0);
}

// ---------------------------------------------------------------------------
// prep_k: fused detect + X-convert + bias-concat + 4x weight transpose.
// Every block re-derives the dtype flag from X[0:256] via ballot popcount.
// Block layout: [0,4096) xcvt | [4096,4112) biascat | [4112,5136) transpose.
// ---------------------------------------------------------------------------
__global__ __launch_bounds__(256) void prep_k(const void* __restrict__ X,
                                              const void* __restrict__ w0,
                                              const void* __restrict__ w1,
                                              const void* __restrict__ w2,
                                              const void* __restrict__ w3,
                                              const void* __restrict__ bq,
                                              const void* __restrict__ bk,
                                              const void* __restrict__ bv,
                                              const void* __restrict__ bo,
                                              ushort* __restrict__ xc,
                                              ushort* __restrict__ biasout,
                                              ushort* __restrict__ wtall,
                                              int* __restrict__ flag) {
    __shared__ int tot;
    __shared__ ushort tile[64][72];
    int t = threadIdx.x;
    if (t == 0) tot = 0;
    __syncthreads();
    uint wv = ((const uint*)X)[t];
    uint e = (wv >> 7) & 0xFFu;
    bool isbf = (e >= 100u && e <= 130u);
    unsigned long long m = __ballot(isbf);
    if ((t & 63) == 0) atomicAdd(&tot, __popcll(m));
    __syncthreads();
    bool isf = (tot <= 128);   // true -> fp32 input

    int bi = blockIdx.x;
    if (bi == 0 && t == 0) flag[0] = isf ? 1 : 0;

    if (bi < 4096) {
        if (!isf) return;
        int i = (bi * 256 + t) * 4;
        float4 v = *(const float4*)((const float*)X + i);
        ushort4 o;
        o.x = f2bf(v.x); o.y = f2bf(v.y); o.z = f2bf(v.z); o.w = f2bf(v.w);
        *(ushort4*)(xc + i) = o;
    } else if (bi < 4112) {
        int i = (bi - 4096) * 256 + t;
        int sel = i >> 10, j = i & 1023;
        const void* p = (sel == 0) ? bq : (sel == 1) ? bk : (sel == 2) ? bv : bo;
        biasout[i] = isf ? f2bf(((const float*)p)[j]) : ((const ushort*)p)[j];
    } else {
        int idx = bi - 4112;
        int z = idx >> 8, rem = idx & 255;
        const void* in = (z == 0) ? w0 : (z == 1) ? w1 : (z == 2) ? w2 : w3;
        ushort* out = wtall + (size_t)z * 1024 * 1024;
        int k0 = (rem & 15) * 64, n0 = (rem >> 4) * 64;
        int r = t >> 3, c = (t & 7) * 8;
#pragma unroll
        for (int p = 0; p < 2; p++) {
            int rr = r + p * 32;
            if (isf) {
                const float* src = (const float*)in + (size_t)(k0 + rr) * 1024 + n0 + c;
                float4 v0 = *(const float4*)src;
                float4 v1 = *(const float4*)(src + 4);
                tile[rr][c + 0] = f2bf(v0.x); tile[rr][c + 1] = f2bf(v0.y);
                tile[rr][c + 2] = f2bf(v0.z); tile[rr][c + 3] = f2bf(v0.w);
                tile[rr][c + 4] = f2bf(v1.x); tile[rr][c + 5] = f2bf(v1.y);
                tile[rr][c + 6] = f2bf(v1.z); tile[rr][c + 7] = f2bf(v1.w);
            } else {
                uint4 v = *(const uint4*)((const ushort*)in + (size_t)(k0 + rr) * 1024 + n0 + c);
                *(uint4*)&tile[rr][c] = v;
            }
        }
        __syncthreads();
#pragma unroll
        for (int p = 0; p < 2; p++) {
            int n = r + p * 32;
            ushort vals[8];
#pragma unroll
            for (int j = 0; j < 8; j++) vals[j] = tile[c + j][n];
            *(uint4*)(out + (size_t)(n0 + n) * 1024 + k0 + c) = *(uint4*)vals;
        }
    }
}

// ---------------------------------------------------------------------------
// V transpose: VT[bh][d][t] = QKV[b*1024+t][2048 + h*64 + d]
// ---------------------------------------------------------------------------
__global__ __launch_bounds__(256) void vtrans_k(const ushort* __restrict__ qkv,
                                                ushort* __restrict__ vt) {
    __shared__ ushort tile[64][72];
    int t0 = blockIdx.x * 64;
    int bh = blockIdx.y;
    int b = bh >> 4, h = bh & 15;
    int t = threadIdx.x;
    int r = t >> 3, c = (t & 7) * 8;
#pragma unroll
    for (int p = 0; p < 2; p++) {
        int rr = r + p * 32;
        uint4 v = *(const uint4*)(qkv + (size_t)(b * 1024 + t0 + rr) * NQKV + 2048 + h * 64 + c);
        *(uint4*)&tile[rr][c] = v;
    }
    __syncthreads();
#pragma unroll
    for (int p = 0; p < 2; p++) {
        int d = r + p * 32;
        ushort vals[8];
#pragma unroll
        for (int j = 0; j < 8; j++) vals[j] = tile[c + j][d];
        *(uint4*)(vt + ((size_t)bh * 64 + d) * 1024 + t0 + c) = *(uint4*)vals;
    }
}

// ---------------------------------------------------------------------------
// GEMM, BK=32 DOUBLE-BUFFERED, single barrier per K-iter (R5 attn pattern):
// at iter top, barrier (buf[cur] staged AND buf[cur^1] reads done), then
// issue stage of kt+1 into buf[cur^1], then compute on buf[cur] -> staging
// latency hidden behind 16-32 MFMA + ds_reads. BM x 128 tile, 4 waves (2x2).
// Chunk swizzle slot = kc ^ ((row>>1)&3) (conflict-free, R7-verified).
// A-pointer selected device-side per *flag. DUAL: fp32/bf16 store per flag.
// ---------------------------------------------------------------------------
template <int BM, bool DUAL>
__global__ __launch_bounds__(256) void gemm_k(const ushort* __restrict__ Araw,
                                              const ushort* __restrict__ Aconv,
                                              const ushort* __restrict__ BT,
                                              const ushort* __restrict__ bias,
                                              void* __restrict__ C,
                                              const int* __restrict__ flag,
                                              int M, int N, int K) {
    constexpr int RM = BM / 32;   // M-frags per wave
    constexpr int AJ = BM / 64;   // A-chunks per thread (BM*4/256)
    __shared__ ushort As[2][BM * 32];
    __shared__ ushort Bs[2][128 * 32];
    int n0 = blockIdx.x * 128, m0 = blockIdx.y * BM;
    int t = threadIdx.x;
    int w = t >> 6, lane = t & 63, q = lane >> 4, ln = lane & 15;
    int wr = w >> 1, wc = w & 1;
    const ushort* A = (*flag) ? Aconv : Araw;

    float4v acc[RM][4];
#pragma unroll
    for (int r = 0; r < RM; r++)
#pragma unroll
        for (int cc = 0; cc < 4; cc++) acc[r][cc] = (float4v){0.f, 0.f, 0.f, 0.f};

    // prologue: stage k0=0 into buf 0
#pragma unroll
    for (int j = 0; j < AJ; j++) {
        int c = j * 256 + t;
        int row = c >> 2, s = c & 3;
        int kc = s ^ ((row >> 1) & 3);
        gl2lds16(A + (size_t)(m0 + row) * K + kc * 8, &As[0][c * 8]);
    }
#pragma unroll
    for (int j = 0; j < 2; j++) {
        int c = j * 256 + t;
        int row = c >> 2, s = c & 3;
        int kc = s ^ ((row >> 1) & 3);
        gl2lds16(BT + (size_t)(n0 + row) * K + kc * 8, &Bs[0][c * 8]);
    }

    int nIter = K >> 5;
    for (int kt = 0; kt < nIter; kt++) {
        int cur = kt & 1;
        __syncthreads();   // buf[cur] staged; buf[cur^1] reads complete
        if (kt + 1 < nIter) {
            int nk0 = (kt + 1) << 5, nxt = cur ^ 1;
#pragma unroll
            for (int j = 0; j < AJ; j++) {
                int c = j * 256 + t;
                int row = c >> 2, s = c & 3;
                int kc = s ^ ((row >> 1) & 3);
                gl2lds16(A + (size_t)(m0 + row) * K + nk0 + kc * 8, &As[nxt][c * 8]);
            }
#pragma unroll
            for (int j = 0; j < 2; j++) {
                int c = j * 256 + t;
                int row = c >> 2, s = c & 3;
                int kc = s ^ ((row >> 1) & 3);
                gl2lds16(BT + (size_t)(n0 + row) * K + nk0 + kc * 8, &Bs[nxt][c * 8]);
            }
        }
        short8 af[RM], bf[4];
#pragma unroll
        for (int r = 0; r < RM; r++) {
            int row = wr * (BM / 2) + r * 16 + ln;
            af[r] = *(const short8*)&As[cur][((row << 2) | (q ^ ((row >> 1) & 3))) * 8];
        }
#pragma unroll
        for (int cc = 0; cc < 4; cc++) {
            int col = wc * 64 + cc * 16 + ln;
            bf[cc] = *(const short8*)&Bs[cur][((col << 2) | (q ^ ((col >> 1) & 3))) * 8];
        }
#pragma unroll
        for (int r = 0; r < RM; r++)
#pragma unroll
            for (int cc = 0; cc < 4; cc++)
                acc[r][cc] = __builtin_amdgcn_mfma_f32_16x16x32_bf16(af[r], bf[cc], acc[r][cc], 0, 0, 0);
    }

    bool outf = DUAL && (*flag != 0);
#pragma unroll
    for (int cc = 0; cc < 4; cc++) {
        int n = n0 + wc * 64 + cc * 16 + ln;
        float bs = bf2f(bias[n]);
#pragma unroll
        for (int r = 0; r < RM; r++) {
#pragma unroll
            for (int i = 0; i < 4; i++) {
                int m = m0 + wr * (BM / 2) + r * 16 + q * 4 + i;
                float v = acc[r][cc][i] + bs;
                if (outf) ((float*)C)[(size_t)m * N + n] = v;
                else      ((ushort*)C)[(size_t)m * N + n] = f2bf(v);
            }
        }
    }
}

// ---------------------------------------------------------------------------
// Flash attention, causal, WAVE-SPLIT shared-prefix dual-tile, pipelined,
// no-max softmax. Grid (8,64) x 512 threads: waves 0-3 own q-tile A = pr,
// waves 4-7 own q-tile B = 15-pr. ONE kt loop stages each K/V block ONCE
// (double-buffered global_load_lds, swizzled); wave-uniform compute gating.
// No-max softmax: p = exp2(s*CE), per-lane l partials, epilogue reduce.
// Faithful reshape: z[b,h,s,d] -> Z'[b][h*64 + s/16][(s%16)*64 + d]
// ---------------------------------------------------------------------------
__global__ __launch_bounds__(512) void attn_k(const ushort* __restrict__ qkv,
                                              const ushort* __restrict__ vt,
                                              ushort* __restrict__ zp) {
    __shared__ ushort Ks[2][64 * 64];
    __shared__ ushort Vs[2][64 * 64];
    __shared__ ushort P[8][16 * 76];
    int pr = blockIdx.x;
    int bh = blockIdx.y;
    int b = bh >> 4, h = bh & 15;
    int t = threadIdx.x;
    int w = t >> 6;
    int grp = w >> 2;
    int lane = t & 63, q = lane >> 4, ln = lane & 15;

    const float CE = 0.72134752f;    // 0.5 * log2(e)

    const ushort* Qp = qkv + (size_t)(b * SEQ) * NQKV + h * 64;
    const ushort* Kp = qkv + (size_t)(b * SEQ) * NQKV + 1024 + h * 64;
    const ushort* Vt = vt + (size_t)bh * 64 * 1024;

    int row0 = t >> 3, kc0 = (t & 7) ^ (row0 & 7);

    int tiB = 15 - pr;
    int ti = grp ? tiB : pr;
    int sw = ti * 64 + (w & 3) * 16;

    short8 aq0 = *(const short8*)(Qp + (size_t)(sw + ln) * NQKV + q * 8);
    short8 aq1 = *(const short8*)(Qp + (size_t)(sw + ln) * NQKV + 32 + q * 8);

    float lp[4];
    float4v o[4];
#pragma unroll
    for (int i = 0; i < 4; i++) lp[i] = 0.f;
#pragma unroll
    for (int nb = 0; nb < 4; nb++) o[nb] = (float4v){0.f, 0.f, 0.f, 0.f};

    gl2lds16(Kp + (size_t)row0 * NQKV + kc0 * 8, &Ks[0][t * 8]);
    gl2lds16(Vt + (size_t)row0 * 1024 + kc0 * 8, &Vs[0][t * 8]);

    for (int kt = 0; kt <= tiB; kt++) {
        int cur = kt & 1;
        int t0 = kt * 64;
        __syncthreads();
        if (kt < tiB) {
            int nt0 = t0 + 64, nxt = cur ^ 1;
            gl2lds16(Kp + (size_t)(nt0 + row0) * NQKV + kc0 * 8, &Ks[nxt][t * 8]);
            gl2lds16(Vt + (size_t)row0 * 1024 + nt0 + kc0 * 8, &Vs[nxt][t * 8]);
        }
        if (kt <= ti) {
            float4v s[4];
#pragma unroll
            for (int nb = 0; nb < 4; nb++) {
                int row = nb * 16 + ln;
                short8 kf0 = *(const short8*)&Ks[cur][((row << 3) | (q ^ (row & 7))) * 8];
                short8 kf1 = *(const short8*)&Ks[cur][((row << 3) | ((4 + q) ^ (row & 7))) * 8];
                s[nb] = (float4v){0.f, 0.f, 0.f, 0.f};
                s[nb] = __builtin_amdgcn_mfma_f32_16x16x32_bf16(aq0, kf0, s[nb], 0, 0, 0);
                s[nb] = __builtin_amdgcn_mfma_f32_16x16x32_bf16(aq1, kf1, s[nb], 0, 0, 0);
            }
            float p[4][4];
            if (kt < ti) {
#pragma unroll
                for (int nb = 0; nb < 4; nb++)
#pragma unroll
                    for (int i = 0; i < 4; i++) p[nb][i] = exp2f(s[nb][i] * CE);
            } else {
#pragma unroll
                for (int nb = 0; nb < 4; nb++)
#pragma unroll
                    for (int i = 0; i < 4; i++) {
                        int srow = sw + q * 4 + i;
                        int col = t0 + nb * 16 + ln;
                        p[nb][i] = exp2f((col <= srow) ? s[nb][i] * CE : -1e30f);
                    }
            }
#pragma unroll
            for (int i = 0; i < 4; i++)
                lp[i] += (p[0][i] + p[1][i]) + (p[2][i] + p[3][i]);
#pragma unroll
            for (int nb = 0; nb < 4; nb++)
#pragma unroll
                for (int i = 0; i < 4; i++)
                    P[w][(q * 4 + i) * 76 + nb * 16 + ln] = f2bf(p[nb][i]);
            asm volatile("s_waitcnt lgkmcnt(0)\n" ::: "memory");
            short8 ap0 = *(const short8*)&P[w][ln * 76 + q * 8];
            short8 ap1 = *(const short8*)&P[w][ln * 76 + 32 + q * 8];
#pragma unroll
            for (int nb = 0; nb < 4; nb++) {
                int row = nb * 16 + ln;
                short8 bv0 = *(const short8*)&Vs[cur][((row << 3) | (q ^ (row & 7))) * 8];
                short8 bv1 = *(const short8*)&Vs[cur][((row << 3) | ((4 + q) ^ (row & 7))) * 8];
                o[nb] = __builtin_amdgcn_mfma_f32_16x16x32_bf16(ap0, bv0, o[nb], 0, 0, 0);
                o[nb] = __builtin_amdgcn_mfma_f32_16x16x32_bf16(ap1, bv1, o[nb], 0, 0, 0);
            }
        }
    }

    float l_i[4];
#pragma unroll
    for (int i = 0; i < 4; i++) {
        float s = lp[i];
#pragma unroll
        for (int mk = 1; mk < 16; mk <<= 1) s += __shfl_xor(s, mk, 64);
        l_i[i] = s;
    }
#pragma unroll
    for (int nb = 0; nb < 4; nb++) {
#pragma unroll
        for (int i = 0; i < 4; i++) {
            int srow = sw + q * 4 + i;
            int d = nb * 16 + ln;
            float z = o[nb][i] / l_i[i];
            int sp = h * 64 + (srow >> 4);
            int ep = ((srow & 15) << 6) + d;
            zp[((size_t)(b * SEQ + sp)) * 1024 + ep] = f2bf(z);
        }
    }
}

// ---------------------------------------------------------------------------
extern "C" void kernel_launch(void* const* d_in, const int* in_sizes, int n_in,
                              void* d_out, int out_size, void* d_ws, size_t ws_size,
                              hipStream_t stream) {
    const void* X  = d_in[0];
    // d_in[1] = mask (causal; applied structurally)
    const void* wq = d_in[2];
    const void* bq = d_in[3];
    const void* wk = d_in[4];
    const void* bk = d_in[5];
    const void* wv = d_in[6];
    const void* bv = d_in[7];
    const void* wo = d_in[8];
    const void* bo = d_in[9];

    char* ws = (char*)d_ws;
    int*    flag  = (int*)ws;                          // [0, 4096)
    ushort* biasq = (ushort*)(ws + 4096);              // 4096 bf16: [bq|bk|bv|bo]
    ushort* WTall = (ushort*)(ws + 12288);             // 4x 1024x1024 bf16 [wq|wk|wv|wo]
    ushort* Xc    = (ushort*)(ws + 8400896);           // 4096x1024 bf16 (fp32 path)
    ushort* QKV   = (ushort*)(ws + 16789504);          // 4096x3072 bf16
    ushort* VT    = (ushort*)(ws + 41955328);          // 64 x 64 x 1024 bf16
    ushort* WTo   = WTall + 3 * 1024 * 1024;
    ushort* ZP    = Xc;                                // alias: Xc dead after QKV gemm

    prep_k<<<5136, 256, 0, stream>>>(X, wq, wk, wv, wo, bq, bk, bv, bo,
                                     Xc, biasq, WTall, flag);
    gemm_k<128, false><<<dim3(24, 32), 256, 0, stream>>>(
        (const ushort*)X, Xc, WTall, biasq, QKV, flag, 4096, NQKV, 1024);
    vtrans_k<<<dim3(16, 64), 256, 0, stream>>>(QKV, VT);
    attn_k<<<dim3(8, 64), 512, 0, stream>>>(QKV, VT, ZP);
    gemm_k<64, true><<<dim3(8, 64), 256, 0, stream>>>(
        ZP, ZP, WTo, biasq + 3072, d_out, flag, 4096, 1024, 1024);
}

// Round 2
// 187.726 us; speedup vs baseline: 1.0170x; 1.0170x over previous
//
#include <hip/hip_runtime.h>
#include <hip/hip_bf16.h>
#include <stdint.h>

typedef __attribute__((ext_vector_type(8))) short short8;
typedef __attribute__((ext_vector_type(4))) float float4v;

#define SEQ   1024
#define NQKV  3072

__device__ __forceinline__ float bf2f(ushort h) {
    union { uint u; float f; } c; c.u = ((uint)h) << 16; return c.f;
}
__device__ __forceinline__ ushort f2bf(float f) {
    union { uint u; float f; } c; c.f = f;
    uint u = c.u;
    return (ushort)((u + 0x7fffu + ((u >> 16) & 1u)) >> 16);
}
__device__ __forceinline__ uint cvt_pk_bf16(float lo, float hi) {
    uint r;
    asm volatile("v_cvt_pk_bf16_f32 %0, %1, %2" : "=v"(r) : "v"(lo), "v"(hi));
    return r;
}
__device__ __forceinline__ void gl2lds16(const ushort* g, ushort* l) {
    __builtin_amdgcn_global_load_lds(
        (const __attribute__((address_space(1))) unsigned int*)(g),
        (__attribute__((address_space(3))) unsigned int*)(l),
        16, 0, 0);
}

// ---------------------------------------------------------------------------
// prep_k: fused detect + X-convert + bias-concat + 4x weight transpose.
// Every block re-derives the dtype flag from X[0:256] via ballot popcount.
// Block layout: [0,4096) xcvt | [4096,4112) biascat | [4112,5136) transpose.
// ---------------------------------------------------------------------------
__global__ __launch_bounds__(256) void prep_k(const void* __restrict__ X,
                                              const void* __restrict__ w0,
                                              const void* __restrict__ w1,
                                              const void* __restrict__ w2,
                                              const void* __restrict__ w3,
                                              const void* __restrict__ bq,
                                              const void* __restrict__ bk,
                                              const void* __restrict__ bv,
                                              const void* __restrict__ bo,
                                              ushort* __restrict__ xc,
                                              ushort* __restrict__ biasout,
                                              ushort* __restrict__ wtall,
                                              int* __restrict__ flag) {
    __shared__ int tot;
    __shared__ ushort tile[64][72];
    int t = threadIdx.x;
    if (t == 0) tot = 0;
    __syncthreads();
    uint wv = ((const uint*)X)[t];
    uint e = (wv >> 7) & 0xFFu;
    bool isbf = (e >= 100u && e <= 130u);
    unsigned long long m = __ballot(isbf);
    if ((t & 63) == 0) atomicAdd(&tot, __popcll(m));
    __syncthreads();
    bool isf = (tot <= 128);   // true -> fp32 input

    int bi = blockIdx.x;
    if (bi == 0 && t == 0) flag[0] = isf ? 1 : 0;

    if (bi < 4096) {
        if (!isf) return;
        int i = (bi * 256 + t) * 4;
        float4 v = *(const float4*)((const float*)X + i);
        ushort4 o;
        o.x = f2bf(v.x); o.y = f2bf(v.y); o.z = f2bf(v.z); o.w = f2bf(v.w);
        *(ushort4*)(xc + i) = o;
    } else if (bi < 4112) {
        int i = (bi - 4096) * 256 + t;
        int sel = i >> 10, j = i & 1023;
        const void* p = (sel == 0) ? bq : (sel == 1) ? bk : (sel == 2) ? bv : bo;
        biasout[i] = isf ? f2bf(((const float*)p)[j]) : ((const ushort*)p)[j];
    } else {
        int idx = bi - 4112;
        int z = idx >> 8, rem = idx & 255;
        const void* in = (z == 0) ? w0 : (z == 1) ? w1 : (z == 2) ? w2 : w3;
        ushort* out = wtall + (size_t)z * 1024 * 1024;
        int k0 = (rem & 15) * 64, n0 = (rem >> 4) * 64;
        int r = t >> 3, c = (t & 7) * 8;
#pragma unroll
        for (int p = 0; p < 2; p++) {
            int rr = r + p * 32;
            if (isf) {
                const float* src = (const float*)in + (size_t)(k0 + rr) * 1024 + n0 + c;
                float4 v0 = *(const float4*)src;
                float4 v1 = *(const float4*)(src + 4);
                tile[rr][c + 0] = f2bf(v0.x); tile[rr][c + 1] = f2bf(v0.y);
                tile[rr][c + 2] = f2bf(v0.z); tile[rr][c + 3] = f2bf(v0.w);
                tile[rr][c + 4] = f2bf(v1.x); tile[rr][c + 5] = f2bf(v1.y);
                tile[rr][c + 6] = f2bf(v1.z); tile[rr][c + 7] = f2bf(v1.w);
            } else {
                uint4 v = *(const uint4*)((const ushort*)in + (size_t)(k0 + rr) * 1024 + n0 + c);
                *(uint4*)&tile[rr][c] = v;
            }
        }
        __syncthreads();
#pragma unroll
        for (int p = 0; p < 2; p++) {
            int n = r + p * 32;
            ushort vals[8];
#pragma unroll
            for (int j = 0; j < 8; j++) vals[j] = tile[c + j][n];
            *(uint4*)(out + (size_t)(n0 + n) * 1024 + k0 + c) = *(uint4*)vals;
        }
    }
}

// ---------------------------------------------------------------------------
// V transpose: VT[bh][d][t] = QKV[b*1024+t][2048 + h*64 + d]
// ---------------------------------------------------------------------------
__global__ __launch_bounds__(256) void vtrans_k(const ushort* __restrict__ qkv,
                                                ushort* __restrict__ vt) {
    __shared__ ushort tile[64][72];
    int t0 = blockIdx.x * 64;
    int bh = blockIdx.y;
    int b = bh >> 4, h = bh & 15;
    int t = threadIdx.x;
    int r = t >> 3, c = (t & 7) * 8;
#pragma unroll
    for (int p = 0; p < 2; p++) {
        int rr = r + p * 32;
        uint4 v = *(const uint4*)(qkv + (size_t)(b * 1024 + t0 + rr) * NQKV + 2048 + h * 64 + c);
        *(uint4*)&tile[rr][c] = v;
    }
    __syncthreads();
#pragma unroll
    for (int p = 0; p < 2; p++) {
        int d = r + p * 32;
        ushort vals[8];
#pragma unroll
        for (int j = 0; j < 8; j++) vals[j] = tile[c + j][d];
        *(uint4*)(vt + ((size_t)bh * 64 + d) * 1024 + t0 + c) = *(uint4*)vals;
    }
}

// ---------------------------------------------------------------------------
// GEMM, BK=32 DOUBLE-BUFFERED, single barrier per K-iter (R5 attn pattern):
// at iter top, barrier (buf[cur] staged AND buf[cur^1] reads done), then
// issue stage of kt+1 into buf[cur^1], then compute on buf[cur] -> staging
// latency hidden behind 16-32 MFMA + ds_reads. BM x 128 tile, 4 waves (2x2).
// Chunk swizzle slot = kc ^ ((row>>1)&3) (conflict-free, R7-verified).
// A-pointer selected device-side per *flag. DUAL: fp32/bf16 store per flag.
// ---------------------------------------------------------------------------
template <int BM, bool DUAL>
__global__ __launch_bounds__(256) void gemm_k(const ushort* __restrict__ Araw,
                                              const ushort* __restrict__ Aconv,
                                              const ushort* __restrict__ BT,
                                              const ushort* __restrict__ bias,
                                              void* __restrict__ C,
                                              const int* __restrict__ flag,
                                              int M, int N, int K) {
    constexpr int RM = BM / 32;   // M-frags per wave
    constexpr int AJ = BM / 64;   // A-chunks per thread (BM*4/256)
    __shared__ ushort As[2][BM * 32];
    __shared__ ushort Bs[2][128 * 32];
    int n0 = blockIdx.x * 128, m0 = blockIdx.y * BM;
    int t = threadIdx.x;
    int w = t >> 6, lane = t & 63, q = lane >> 4, ln = lane & 15;
    int wr = w >> 1, wc = w & 1;
    const ushort* A = (*flag) ? Aconv : Araw;

    float4v acc[RM][4];
#pragma unroll
    for (int r = 0; r < RM; r++)
#pragma unroll
        for (int cc = 0; cc < 4; cc++) acc[r][cc] = (float4v){0.f, 0.f, 0.f, 0.f};

    // prologue: stage k0=0 into buf 0
#pragma unroll
    for (int j = 0; j < AJ; j++) {
        int c = j * 256 + t;
        int row = c >> 2, s = c & 3;
        int kc = s ^ ((row >> 1) & 3);
        gl2lds16(A + (size_t)(m0 + row) * K + kc * 8, &As[0][c * 8]);
    }
#pragma unroll
    for (int j = 0; j < 2; j++) {
        int c = j * 256 + t;
        int row = c >> 2, s = c & 3;
        int kc = s ^ ((row >> 1) & 3);
        gl2lds16(BT + (size_t)(n0 + row) * K + kc * 8, &Bs[0][c * 8]);
    }

    int nIter = K >> 5;
    for (int kt = 0; kt < nIter; kt++) {
        int cur = kt & 1;
        __syncthreads();   // buf[cur] staged; buf[cur^1] reads complete
        if (kt + 1 < nIter) {
            int nk0 = (kt + 1) << 5, nxt = cur ^ 1;
#pragma unroll
            for (int j = 0; j < AJ; j++) {
                int c = j * 256 + t;
                int row = c >> 2, s = c & 3;
                int kc = s ^ ((row >> 1) & 3);
                gl2lds16(A + (size_t)(m0 + row) * K + nk0 + kc * 8, &As[nxt][c * 8]);
            }
#pragma unroll
            for (int j = 0; j < 2; j++) {
                int c = j * 256 + t;
                int row = c >> 2, s = c & 3;
                int kc = s ^ ((row >> 1) & 3);
                gl2lds16(BT + (size_t)(n0 + row) * K + nk0 + kc * 8, &Bs[nxt][c * 8]);
            }
        }
        short8 af[RM], bf[4];
#pragma unroll
        for (int r = 0; r < RM; r++) {
            int row = wr * (BM / 2) + r * 16 + ln;
            af[r] = *(const short8*)&As[cur][((row << 2) | (q ^ ((row >> 1) & 3))) * 8];
        }
#pragma unroll
        for (int cc = 0; cc < 4; cc++) {
            int col = wc * 64 + cc * 16 + ln;
            bf[cc] = *(const short8*)&Bs[cur][((col << 2) | (q ^ ((col >> 1) & 3))) * 8];
        }
#pragma unroll
        for (int r = 0; r < RM; r++)
#pragma unroll
            for (int cc = 0; cc < 4; cc++)
                acc[r][cc] = __builtin_amdgcn_mfma_f32_16x16x32_bf16(af[r], bf[cc], acc[r][cc], 0, 0, 0);
    }

    bool outf = DUAL && (*flag != 0);
#pragma unroll
    for (int cc = 0; cc < 4; cc++) {
        int n = n0 + wc * 64 + cc * 16 + ln;
        float bs = bf2f(bias[n]);
#pragma unroll
        for (int r = 0; r < RM; r++) {
#pragma unroll
            for (int i = 0; i < 4; i++) {
                int m = m0 + wr * (BM / 2) + r * 16 + q * 4 + i;
                float v = acc[r][cc][i] + bs;
                if (outf) ((float*)C)[(size_t)m * N + n] = v;
                else      ((ushort*)C)[(size_t)m * N + n] = f2bf(v);
            }
        }
    }
}

// ---------------------------------------------------------------------------
// Flash attention, causal, WAVE-SPLIT shared-prefix dual-tile, pipelined,
// no-max softmax. Grid (8,64) x 512 threads: waves 0-3 own q-tile A = pr,
// waves 4-7 own q-tile B = 15-pr. ONE kt loop stages each K/V block ONCE
// (double-buffered global_load_lds, swizzled); wave-uniform compute gating.
// SWAPPED QK^T (T12): s = mfma(K, Q) so each lane holds S[t=nb*16+q*4+i]
// [srow=ln] -> P-write is 4x ds_write_b64 via v_cvt_pk_bf16_f32 (was 16x
// scalar b16), l-partial is one scalar per lane (reduce over q at epilogue).
// A/B fragment layouts for 16x16x32 are identical per-lane, so the Ks/aq
// loads are unchanged; only mfma operand order flips.
// Faithful reshape: z[b,h,s,d] -> Z'[b][h*64 + s/16][(s%16)*64 + d]
// ---------------------------------------------------------------------------
__global__ __launch_bounds__(512) void attn_k(const ushort* __restrict__ qkv,
                                              const ushort* __restrict__ vt,
                                              ushort* __restrict__ zp) {
    __shared__ ushort Ks[2][64 * 64];
    __shared__ ushort Vs[2][64 * 64];
    __shared__ ushort P[8][16 * 76];
    int pr = blockIdx.x;
    int bh = blockIdx.y;
    int b = bh >> 4, h = bh & 15;
    int t = threadIdx.x;
    int w = t >> 6;
    int grp = w >> 2;
    int lane = t & 63, q = lane >> 4, ln = lane & 15;

    const float CE = 0.72134752f;    // 0.5 * log2(e)

    const ushort* Qp = qkv + (size_t)(b * SEQ) * NQKV + h * 64;
    const ushort* Kp = qkv + (size_t)(b * SEQ) * NQKV + 1024 + h * 64;
    const ushort* Vt = vt + (size_t)bh * 64 * 1024;

    int row0 = t >> 3, kc0 = (t & 7) ^ (row0 & 7);

    int tiB = 15 - pr;
    int ti = grp ? tiB : pr;
    int sw = ti * 64 + (w & 3) * 16;

    short8 aq0 = *(const short8*)(Qp + (size_t)(sw + ln) * NQKV + q * 8);
    short8 aq1 = *(const short8*)(Qp + (size_t)(sw + ln) * NQKV + 32 + q * 8);

    float lp = 0.f;
    float4v o[4];
#pragma unroll
    for (int nb = 0; nb < 4; nb++) o[nb] = (float4v){0.f, 0.f, 0.f, 0.f};

    gl2lds16(Kp + (size_t)row0 * NQKV + kc0 * 8, &Ks[0][t * 8]);
    gl2lds16(Vt + (size_t)row0 * 1024 + kc0 * 8, &Vs[0][t * 8]);

    int srow_l = sw + ln;   // this lane's q-row (post-swap: srow = ln axis)

    for (int kt = 0; kt <= tiB; kt++) {
        int cur = kt & 1;
        int t0 = kt * 64;
        __syncthreads();
        if (kt < tiB) {
            int nt0 = t0 + 64, nxt = cur ^ 1;
            gl2lds16(Kp + (size_t)(nt0 + row0) * NQKV + kc0 * 8, &Ks[nxt][t * 8]);
            gl2lds16(Vt + (size_t)row0 * 1024 + nt0 + kc0 * 8, &Vs[nxt][t * 8]);
        }
        if (kt <= ti) {
            float4v s[4];
#pragma unroll
            for (int nb = 0; nb < 4; nb++) {
                int row = nb * 16 + ln;
                short8 kf0 = *(const short8*)&Ks[cur][((row << 3) | (q ^ (row & 7))) * 8];
                short8 kf1 = *(const short8*)&Ks[cur][((row << 3) | ((4 + q) ^ (row & 7))) * 8];
                s[nb] = (float4v){0.f, 0.f, 0.f, 0.f};
                s[nb] = __builtin_amdgcn_mfma_f32_16x16x32_bf16(kf0, aq0, s[nb], 0, 0, 0);
                s[nb] = __builtin_amdgcn_mfma_f32_16x16x32_bf16(kf1, aq1, s[nb], 0, 0, 0);
            }
            float p[4][4];
            if (kt < ti) {
#pragma unroll
                for (int nb = 0; nb < 4; nb++)
#pragma unroll
                    for (int i = 0; i < 4; i++) p[nb][i] = exp2f(s[nb][i] * CE);
            } else {
#pragma unroll
                for (int nb = 0; nb < 4; nb++)
#pragma unroll
                    for (int i = 0; i < 4; i++) {
                        int tcol = t0 + nb * 16 + q * 4 + i;
                        p[nb][i] = exp2f((tcol <= srow_l) ? s[nb][i] * CE : -1e30f);
                    }
            }
#pragma unroll
            for (int nb = 0; nb < 4; nb++)
                lp += (p[nb][0] + p[nb][1]) + (p[nb][2] + p[nb][3]);
#pragma unroll
            for (int nb = 0; nb < 4; nb++) {
                uint2 pk;
                pk.x = cvt_pk_bf16(p[nb][0], p[nb][1]);
                pk.y = cvt_pk_bf16(p[nb][2], p[nb][3]);
                *(uint2*)&P[w][ln * 76 + nb * 16 + q * 4] = pk;
            }
            asm volatile("s_waitcnt lgkmcnt(0)\n" ::: "memory");
            short8 ap0 = *(const short8*)&P[w][ln * 76 + q * 8];
            short8 ap1 = *(const short8*)&P[w][ln * 76 + 32 + q * 8];
#pragma unroll
            for (int nb = 0; nb < 4; nb++) {
                int row = nb * 16 + ln;
                short8 bv0 = *(const short8*)&Vs[cur][((row << 3) | (q ^ (row & 7))) * 8];
                short8 bv1 = *(const short8*)&Vs[cur][((row << 3) | ((4 + q) ^ (row & 7))) * 8];
                o[nb] = __builtin_amdgcn_mfma_f32_16x16x32_bf16(ap0, bv0, o[nb], 0, 0, 0);
                o[nb] = __builtin_amdgcn_mfma_f32_16x16x32_bf16(ap1, bv1, o[nb], 0, 0, 0);
            }
        }
    }

    // l[srow=ln] lives per-lane; reduce partial sums across the q axis.
    float lred = lp;
    lred += __shfl_xor(lred, 16, 64);
    lred += __shfl_xor(lred, 32, 64);
    // broadcast l for the o-fragment rows (srow = sw + q*4 + i)
    float l_i[4];
#pragma unroll
    for (int i = 0; i < 4; i++)
        l_i[i] = __shfl(lred, (q << 4) | (q * 4 + i), 64);

#pragma unroll
    for (int nb = 0; nb < 4; nb++) {
#pragma unroll
        for (int i = 0; i < 4; i++) {
            int srow = sw + q * 4 + i;
            int d = nb * 16 + ln;
            float z = o[nb][i] / l_i[i];
            int sp = h * 64 + (srow >> 4);
            int ep = ((srow & 15) << 6) + d;
            zp[((size_t)(b * SEQ + sp)) * 1024 + ep] = f2bf(z);
        }
    }
}

// ---------------------------------------------------------------------------
extern "C" void kernel_launch(void* const* d_in, const int* in_sizes, int n_in,
                              void* d_out, int out_size, void* d_ws, size_t ws_size,
                              hipStream_t stream) {
    const void* X  = d_in[0];
    // d_in[1] = mask (causal; applied structurally)
    const void* wq = d_in[2];
    const void* bq = d_in[3];
    const void* wk = d_in[4];
    const void* bk = d_in[5];
    const void* wv = d_in[6];
    const void* bv = d_in[7];
    const void* wo = d_in[8];
    const void* bo = d_in[9];

    char* ws = (char*)d_ws;
    int*    flag  = (int*)ws;                          // [0, 4096)
    ushort* biasq = (ushort*)(ws + 4096);              // 4096 bf16: [bq|bk|bv|bo]
    ushort* WTall = (ushort*)(ws + 12288);             // 4x 1024x1024 bf16 [wq|wk|wv|wo]
    ushort* Xc    = (ushort*)(ws + 8400896);           // 4096x1024 bf16 (fp32 path)
    ushort* QKV   = (ushort*)(ws + 16789504);          // 4096x3072 bf16
    ushort* VT    = (ushort*)(ws + 41955328);          // 64 x 64 x 1024 bf16
    ushort* WTo   = WTall + 3 * 1024 * 1024;
    ushort* ZP    = Xc;                                // alias: Xc dead after QKV gemm

    prep_k<<<5136, 256, 0, stream>>>(X, wq, wk, wv, wo, bq, bk, bv, bo,
                                     Xc, biasq, WTall, flag);
    gemm_k<128, false><<<dim3(24, 32), 256, 0, stream>>>(
        (const ushort*)X, Xc, WTall, biasq, QKV, flag, 4096, NQKV, 1024);
    vtrans_k<<<dim3(16, 64), 256, 0, stream>>>(QKV, VT);
    attn_k<<<dim3(8, 64), 512, 0, stream>>>(QKV, VT, ZP);
    gemm_k<64, true><<<dim3(8, 64), 256, 0, stream>>>(
        ZP, ZP, WTo, biasq + 3072, d_out, flag, 4096, 1024, 1024);
}